// Round 1
// 617.150 us; speedup vs baseline: 1.0298x; 1.0298x over previous
//
#include <hip/hip_runtime.h>
#include <hip/hip_bf16.h>
#include <math.h>

// Problem constants (B=4, C=1024, d=1024)
#define T_TOK 4096
#define D     1024
#define DFF   4096
#define NEXP  8
#define CAP   1280   // floor(2*1.25*4096/8)=1280, already even
#define TOPK  2

typedef __bf16 bf16x8 __attribute__((ext_vector_type(8)));
typedef float floatx4 __attribute__((ext_vector_type(4)));

__device__ __forceinline__ unsigned short f2bf(float f) {
  union { float f; unsigned u; } un; un.f = f;
  unsigned r = un.u + 0x7FFF + ((un.u >> 16) & 1);  // RNE
  return (unsigned short)(r >> 16);
}

// ---------------------------------------------------------------------------
// Router (unchanged, verified): top-2, lowest-index tie-break, softmax.
// ---------------------------------------------------------------------------
__global__ __launch_bounds__(256) void router_kernel(
    const float* __restrict__ x, const float* __restrict__ wg,
    int* __restrict__ top_e, float* __restrict__ top_p) {
  int t = blockIdx.x * 4 + (threadIdx.x >> 6);
  int lane = threadIdx.x & 63;
  if (t >= T_TOK) return;
  const float* xr = x + (size_t)t * D;
  float acc[NEXP];
#pragma unroll
  for (int e = 0; e < NEXP; e++) acc[e] = 0.f;
  for (int dd = lane; dd < D; dd += 64) {
    float xv = xr[dd];
    const float* wr = wg + dd * NEXP;
#pragma unroll
    for (int e = 0; e < NEXP; e++) acc[e] += xv * wr[e];
  }
#pragma unroll
  for (int off = 32; off > 0; off >>= 1) {
#pragma unroll
    for (int e = 0; e < NEXP; e++) acc[e] += __shfl_xor(acc[e], off, 64);
  }
  if (lane == 0) {
    int b0 = 0; float v0 = acc[0];
    for (int e = 1; e < NEXP; e++) if (acc[e] > v0) { v0 = acc[e]; b0 = e; }
    int b1 = -1; float v1 = -INFINITY;
    for (int e = 0; e < NEXP; e++) if (e != b0 && acc[e] > v1) { v1 = acc[e]; b1 = e; }
    float e1 = expf(v1 - v0);
    float s = 1.0f + e1;
    top_e[t * 2 + 0] = b0; top_e[t * 2 + 1] = b1;
    top_p[t * 2 + 0] = 1.0f / s; top_p[t * 2 + 1] = e1 / s;
  }
}

// ---------------------------------------------------------------------------
// Rank/capacity (unchanged, verified): nanoMoE cumsum semantics via wave scans.
// ---------------------------------------------------------------------------
__global__ __launch_bounds__(1024) void rank_kernel(
    const int* __restrict__ top_e, const float* __restrict__ top_p,
    int* __restrict__ slot_token, int* __restrict__ tok_slot,
    float* __restrict__ tok_w) {
  __shared__ int wsum[16][NEXP];
  __shared__ int wscan[16][NEXP];
  int tid = threadIdx.x;
  int lane = tid & 63, w = tid >> 6;

  for (int s = tid; s < NEXP * CAP; s += 1024) slot_token[s] = -1;
  __syncthreads();  // clear visible before any assignment writes

  int base[NEXP];
#pragma unroll
  for (int e = 0; e < NEXP; e++) base[e] = 0;

  for (int k = 0; k < TOPK; k++) {
    int cnt[NEXP];
#pragma unroll
    for (int e = 0; e < NEXP; e++) cnt[e] = 0;
    int eloc[4];
#pragma unroll
    for (int i = 0; i < 4; i++) {
      int t = tid * 4 + i;
      int e = top_e[t * 2 + k];
      eloc[i] = e;
#pragma unroll
      for (int q = 0; q < NEXP; q++) cnt[q] += (q == e);
    }
    // intra-wave inclusive scan (8-wide vector), no barriers
    int inc[NEXP];
#pragma unroll
    for (int e = 0; e < NEXP; e++) inc[e] = cnt[e];
    for (int off = 1; off < 64; off <<= 1) {
#pragma unroll
      for (int e = 0; e < NEXP; e++) {
        int v = __shfl_up(inc[e], off, 64);
        if (lane >= off) inc[e] += v;
      }
    }
    if (lane == 63)
#pragma unroll
      for (int e = 0; e < NEXP; e++) wsum[w][e] = inc[e];
    __syncthreads();
    if (w == 0 && lane < 16) {
      int s[NEXP];
#pragma unroll
      for (int e = 0; e < NEXP; e++) s[e] = wsum[lane][e];
      for (int off = 1; off < 16; off <<= 1) {
#pragma unroll
        for (int e = 0; e < NEXP; e++) {
          int v = __shfl_up(s[e], off, 64);
          if (lane >= off) s[e] += v;
        }
      }
#pragma unroll
      for (int e = 0; e < NEXP; e++) wscan[lane][e] = s[e];
    }
    __syncthreads();
    int excl[NEXP];
#pragma unroll
    for (int e = 0; e < NEXP; e++)
      excl[e] = inc[e] - cnt[e] + (w ? wscan[w - 1][e] : 0) + base[e];

    int run[NEXP];
#pragma unroll
    for (int e = 0; e < NEXP; e++) run[e] = 0;
#pragma unroll
    for (int i = 0; i < 4; i++) {
      int t = tid * 4 + i;
      int e = eloc[i];
      int r = 0;
#pragma unroll
      for (int q = 0; q < NEXP; q++)
        if (q == e) { r = excl[q] + run[q]; run[q]++; }
      if (r < CAP) {
        slot_token[e * CAP + r] = t;
        tok_slot[t * 2 + k] = e * CAP + r;
      } else {
        tok_slot[t * 2 + k] = -1;
      }
      tok_w[t * 2 + k] = top_p[t * 2 + k];
    }
#pragma unroll
    for (int e = 0; e < NEXP; e++) base[e] += wscan[15][e];
    __syncthreads();  // protect wsum/wscan reuse next k
  }
}

// ---------------------------------------------------------------------------
// Gather + fp32->bf16 (unchanged, verified).
// ---------------------------------------------------------------------------
__global__ __launch_bounds__(256) void gather_cvt_kernel(
    const float* __restrict__ x, const int* __restrict__ slot_token,
    unsigned short* __restrict__ xb) {
  int slot = blockIdx.x;
  int tok = slot_token[slot];
  int i = threadIdx.x;
  float4 v = make_float4(0.f, 0.f, 0.f, 0.f);
  if (tok >= 0) v = ((const float4*)(x + (size_t)tok * D))[i];
  ushort4 o;
  o.x = f2bf(v.x); o.y = f2bf(v.y); o.z = f2bf(v.z); o.w = f2bf(v.w);
  ((ushort4*)(xb + (size_t)slot * D))[i] = o;
}

// ---------------------------------------------------------------------------
// Transpose + fp32->bf16, 64x64 tile (unchanged, verified).
// src [E][R][Cc] fp32 -> dst [E][Cc][R] bf16.
// ---------------------------------------------------------------------------
__global__ __launch_bounds__(256) void transpose_cvt_kernel(
    const float* __restrict__ src, unsigned short* __restrict__ dst,
    int R, int Cc) {
  __shared__ float tile[64][65];
  int e = blockIdx.z;
  src += (size_t)e * R * Cc;
  dst += (size_t)e * R * Cc;
  int r0 = blockIdx.y * 64, c0 = blockIdx.x * 64;
  int tr = threadIdx.x >> 4;         // 0..15
  int tc = (threadIdx.x & 15) * 4;   // 0..60
#pragma unroll
  for (int i = 0; i < 64; i += 16) {
    float4 v = *(const float4*)(src + (size_t)(r0 + tr + i) * Cc + c0 + tc);
    tile[tr + i][tc + 0] = v.x;
    tile[tr + i][tc + 1] = v.y;
    tile[tr + i][tc + 2] = v.z;
    tile[tr + i][tc + 3] = v.w;
  }
  __syncthreads();
#pragma unroll
  for (int i = 0; i < 64; i += 16) {
    int c = tr + i, r = tc;
    ushort4 o;
    o.x = f2bf(tile[r + 0][c]);
    o.y = f2bf(tile[r + 1][c]);
    o.z = f2bf(tile[r + 2][c]);
    o.w = f2bf(tile[r + 3][c]);
    *(ushort4*)(dst + (size_t)(c0 + c) * R + r0 + r) = o;
  }
}

// ---------------------------------------------------------------------------
// 256x256 8-phase bf16 MFMA GEMM (T2+T3+T4+T5 template).
//   512 threads = 8 waves (2M x 4N), wave tile 128x64, acc[8][4] 16x16 frags.
//   BK=64 split into two K-halves of 32; 4 phases per K-tile, 16 MFMA each,
//   2 raw s_barriers per phase. LDS = 2dbuf x 2khalf x 256rows x 32k x {A,B}
//   = 128 KiB. Staging granularity = 16 KB half (2 x global_load_lds dwordx4),
//   issued 6 halves ahead of its consumption deadline; counted vmcnt(6) once
//   per K-tile (vmcnt(0) only on the last K-tile).
//   Bank-conflict fix: slot ^= (row>>1)&3 swizzle, applied as pre-swizzled
//   GLOBAL source (global_load_lds dest must stay linear) + swizzled ds_read.
//   MODE 0: h = gelu(xb @ cfc_t^T),   K=1024, 640 blocks (80/XCD = 1 expert).
//   MODE 1: eo = h @ cproj_t^T (fp32), K=4096, 160 blocks (20/XCD = 1 expert).
// ---------------------------------------------------------------------------
template <int MODE>
__global__ __launch_bounds__(512, 2) void gemm8_kernel(
    const unsigned short* __restrict__ A,
    const unsigned short* __restrict__ Bt,
    void* __restrict__ Cv) {
  constexpr int NN   = (MODE == 0) ? DFF : D;   // output cols
  constexpr int KK   = (MODE == 0) ? D : DFF;   // K (row stride of A and Bt)
  constexpr int NTN  = NN / 256;
  constexpr int NKT  = KK / 64;                 // K-tiles
  constexpr int STOT = NKT * 4;                 // total half-tiles
  constexpr int REG  = 256 * 32;                // shorts per (buf,khalf) region

  __shared__ unsigned short As[4 * REG];  // 64 KB
  __shared__ unsigned short Bs[4 * REG];  // 64 KB

  // XCD swizzle: nwg/8 == tiles-per-expert, so each XCD owns one expert.
  int e    = blockIdx.x & 7;
  int idx  = blockIdx.x >> 3;
  int row0 = (idx / NTN) * 256;
  int col0 = (idx % NTN) * 256;

  int tid  = threadIdx.x;
  int lane = tid & 63, wave = tid >> 6;
  int wm = wave >> 2, wn = wave & 3;      // 2 x 4 wave grid
  int fr = lane & 15, fq = lane >> 4;
  // ds_read swizzle: logical k-slot fq lives at physical slot fq^((row>>1)&3);
  // (row>>1)&3 == (fr>>1)&3 for all fragment rows (offsets are mult. of 16).
  int lanesw = (fq ^ ((fr >> 1) & 3)) * 8;  // element offset within 32-el row

  // Staging: thread t writes LDS linear slot (row=t>>2 [+128], phys=t&3);
  // source pre-swizzled so phys slot p holds logical slot p^((row>>1)&3).
  int srow  = tid >> 2;
  int lslot = (tid & 3) ^ ((srow >> 1) & 3);
  const unsigned short* asrc =
      A + (size_t)e * CAP * KK + (size_t)(row0 + srow) * KK + lslot * 8;
  const unsigned short* bsrc =
      Bt + (size_t)e * NN * KK + (size_t)(col0 + srow) * KK + lslot * 8;

  floatx4 acc[8][4];
#pragma unroll
  for (int m = 0; m < 8; m++)
#pragma unroll
    for (int n = 0; n < 4; n++) acc[m][n] = (floatx4){0.f, 0.f, 0.f, 0.f};

  // Half-tile s (deadline order): kt=s>>2; s&3: 0=A kh0, 1=B kh0, 2=A kh1,
  // 3=B kh1. kh0 consumed at phases {0,1} of kt, kh1 at {2,3}.
  auto stage = [&](int s) {
    if (s >= STOT) return;
    int kt = s >> 2, j = s & 3, hh = j >> 1;
    const unsigned short* src = (j & 1) ? bsrc : asrc;
    unsigned short* dst =
        ((j & 1) ? Bs : As) + ((kt & 1) * 2 + hh) * REG + tid * 8;
    size_t go = (size_t)kt * 64 + hh * 32;
    __builtin_amdgcn_global_load_lds(
        (const __attribute__((address_space(1))) unsigned int*)(src + go),
        (__attribute__((address_space(3))) unsigned int*)dst, 16, 0, 0);
    __builtin_amdgcn_global_load_lds(
        (const __attribute__((address_space(1))) unsigned int*)(src + go +
                                                               (size_t)128 * KK),
        (__attribute__((address_space(3))) unsigned int*)(dst + REG / 2), 16, 0,
        0);
  };

  // Prologue: 6 halves in flight (K-tile 0 complete + kh0 of K-tile 1).
#pragma unroll
  for (int s = 0; s < 6; s++) stage(s);

  bf16x8 aq[4], bq[4];

  for (int kt = 0; kt < NKT; kt++) {
    const unsigned short* a0 = As + (kt & 1) * 2 * REG;
    const unsigned short* b0 = Bs + (kt & 1) * 2 * REG;
    const unsigned short* a1 = a0 + REG;
    const unsigned short* b1 = b0 + REG;
    int abase = (wm * 128 + fr) * 32 + lanesw;
    int bbase = (wn * 64 + fr) * 32 + lanesw;

    // ---- phase 0: K-tile boundary. After this phase's issue, exactly 3
    // halves (6 loads) are in flight; vmcnt(6) => this K-tile fully landed.
    stage(kt * 4 + 6);
    if (kt == NKT - 1)
      asm volatile("s_waitcnt vmcnt(0)" ::: "memory");
    else
      asm volatile("s_waitcnt vmcnt(6)" ::: "memory");
    __builtin_amdgcn_s_barrier();
    __builtin_amdgcn_sched_barrier(0);  // no ds_read may hoist above this
#pragma unroll
    for (int n = 0; n < 4; n++)
      bq[n] = *(const bf16x8*)&b0[bbase + n * 512];
#pragma unroll
    for (int m = 0; m < 4; m++)
      aq[m] = *(const bf16x8*)&a0[abase + m * 512];
    __builtin_amdgcn_s_setprio(1);
#pragma unroll
    for (int m = 0; m < 4; m++)
#pragma unroll
      for (int n = 0; n < 4; n++)
        acc[m][n] = __builtin_amdgcn_mfma_f32_16x16x32_bf16(aq[m], bq[n],
                                                            acc[m][n], 0, 0, 0);
    __builtin_amdgcn_s_setprio(0);
    __builtin_amdgcn_s_barrier();

    // ---- phase 1: rows 64..127 of wave tile, kh0 (bq reused).
#pragma unroll
    for (int m = 0; m < 4; m++)
      aq[m] = *(const bf16x8*)&a0[abase + 2048 + m * 512];
    stage(kt * 4 + 7);
    __builtin_amdgcn_s_barrier();
    __builtin_amdgcn_s_setprio(1);
#pragma unroll
    for (int m = 0; m < 4; m++)
#pragma unroll
      for (int n = 0; n < 4; n++)
        acc[4 + m][n] = __builtin_amdgcn_mfma_f32_16x16x32_bf16(
            aq[m], bq[n], acc[4 + m][n], 0, 0, 0);
    __builtin_amdgcn_s_setprio(0);
    __builtin_amdgcn_s_barrier();

    // ---- phase 2: kh1, rows 0..63.
#pragma unroll
    for (int n = 0; n < 4; n++)
      bq[n] = *(const bf16x8*)&b1[bbase + n * 512];
#pragma unroll
    for (int m = 0; m < 4; m++)
      aq[m] = *(const bf16x8*)&a1[abase + m * 512];
    stage(kt * 4 + 8);
    __builtin_amdgcn_s_barrier();
    __builtin_amdgcn_s_setprio(1);
#pragma unroll
    for (int m = 0; m < 4; m++)
#pragma unroll
      for (int n = 0; n < 4; n++)
        acc[m][n] = __builtin_amdgcn_mfma_f32_16x16x32_bf16(aq[m], bq[n],
                                                            acc[m][n], 0, 0, 0);
    __builtin_amdgcn_s_setprio(0);
    __builtin_amdgcn_s_barrier();

    // ---- phase 3: kh1, rows 64..127.
#pragma unroll
    for (int m = 0; m < 4; m++)
      aq[m] = *(const bf16x8*)&a1[abase + 2048 + m * 512];
    stage(kt * 4 + 9);
    __builtin_amdgcn_s_barrier();
    __builtin_amdgcn_s_setprio(1);
#pragma unroll
    for (int m = 0; m < 4; m++)
#pragma unroll
      for (int n = 0; n < 4; n++)
        acc[4 + m][n] = __builtin_amdgcn_mfma_f32_16x16x32_bf16(
            aq[m], bq[n], acc[4 + m][n], 0, 0, 0);
    __builtin_amdgcn_s_setprio(0);
    __builtin_amdgcn_s_barrier();
  }

  // Epilogue. C/D layout: col = lane&15 (fr), row = fq*4 + reg.
  if (MODE == 0) {
    unsigned short* Ce = (unsigned short*)Cv + (size_t)e * CAP * DFF +
                         (size_t)(row0 + wm * 128 + fq * 4) * DFF + col0 +
                         wn * 64 + fr;
#pragma unroll
    for (int m = 0; m < 8; m++)
#pragma unroll
      for (int r = 0; r < 4; r++) {
        size_t ro = (size_t)(m * 16 + r) * DFF;
#pragma unroll
        for (int n = 0; n < 4; n++) {
          float v = acc[m][n][r];
          v = 0.5f * v * (1.f + erff(v * 0.70710678118654752f));
          Ce[ro + n * 16] = f2bf(v);
        }
      }
  } else {
    float* Ce = (float*)Cv + (size_t)e * CAP * D +
                (size_t)(row0 + wm * 128 + fq * 4) * D + col0 + wn * 64 + fr;
#pragma unroll
    for (int m = 0; m < 8; m++)
#pragma unroll
      for (int r = 0; r < 4; r++) {
        size_t ro = (size_t)(m * 16 + r) * D;
#pragma unroll
        for (int n = 0; n < 4; n++) Ce[ro + n * 16] = acc[m][n][r];
      }
  }
}

// ---------------------------------------------------------------------------
// Combine: out[t,:] = sum_k kept(w_k * eo[slot_k,:]). Single eo (no split-K).
// ---------------------------------------------------------------------------
__global__ __launch_bounds__(256) void combine_kernel(
    const float* __restrict__ eo, const int* __restrict__ tok_slot,
    const float* __restrict__ tok_w, float* __restrict__ out) {
  int t = blockIdx.x;
  int i = threadIdx.x;
  float4 acc = make_float4(0.f, 0.f, 0.f, 0.f);
#pragma unroll
  for (int k = 0; k < TOPK; k++) {
    int s = tok_slot[t * 2 + k];
    if (s >= 0) {
      float w = tok_w[t * 2 + k];
      float4 v = ((const float4*)(eo + (size_t)s * D))[i];
      acc.x += w * v.x;
      acc.y += w * v.y;
      acc.z += w * v.z;
      acc.w += w * v.w;
    }
  }
  ((float4*)(out + (size_t)t * D))[i] = acc;
}

// ---------------------------------------------------------------------------
extern "C" void kernel_launch(void* const* d_in, const int* in_sizes, int n_in,
                              void* d_out, int out_size, void* d_ws, size_t ws_size,
                              hipStream_t stream) {
  const float* x     = (const float*)d_in[0];  // [4,1024,1024]
  const float* wg    = (const float*)d_in[1];  // [1024,8]
  const float* cfc   = (const float*)d_in[2];  // [8,1024,4096]
  const float* cproj = (const float*)d_in[3];  // [8,4096,1024]
  float* out = (float*)d_out;

  char* ws = (char*)d_ws;
  size_t off = 0;
  auto alloc = [&](size_t bytes) -> void* {
    void* p = ws + off;
    off += (bytes + 255) & ~(size_t)255;
    return p;
  };
  int*   top_e      = (int*)  alloc((size_t)T_TOK * 2 * 4);
  float* top_p      = (float*)alloc((size_t)T_TOK * 2 * 4);
  int*   slot_token = (int*)  alloc((size_t)NEXP * CAP * 4);
  int*   tok_slot   = (int*)  alloc((size_t)T_TOK * 2 * 4);
  float* tok_w      = (float*)alloc((size_t)T_TOK * 2 * 4);
  unsigned short* xb      = (unsigned short*)alloc((size_t)NEXP * CAP * D * 2);   // 20 MB
  unsigned short* cfc_t   = (unsigned short*)alloc((size_t)NEXP * D * DFF * 2);   // 67 MB [e][DFF][D]
  unsigned short* cproj_t = (unsigned short*)alloc((size_t)NEXP * DFF * D * 2);   // 67 MB [e][D][DFF]
  unsigned short* h       = (unsigned short*)alloc((size_t)NEXP * CAP * DFF * 2); // 84 MB
  // eo [NEXP][CAP][D] fp32 = 42 MB, aliases dead xb/cfc_t region (87.9 MB):
  // GEMM2 reads only h + cproj_t; combine reads eo.
  float* eo = (float*)xb;

  // Weight convert+transpose (independent of routing).
  transpose_cvt_kernel<<<dim3(DFF / 64, D / 64, NEXP), 256, 0, stream>>>(
      cfc, cfc_t, D, DFF);
  transpose_cvt_kernel<<<dim3(D / 64, DFF / 64, NEXP), 256, 0, stream>>>(
      cproj, cproj_t, DFF, D);

  router_kernel<<<T_TOK / 4, 256, 0, stream>>>(x, wg, top_e, top_p);
  rank_kernel<<<1, 1024, 0, stream>>>(top_e, top_p, slot_token, tok_slot, tok_w);
  gather_cvt_kernel<<<NEXP * CAP, 256, 0, stream>>>(x, slot_token, xb);

  // GEMM1: h = gelu(xb @ cfc_t^T). 8*5*16 = 640 blocks.
  gemm8_kernel<0><<<NEXP * (CAP / 256) * (DFF / 256), 512, 0, stream>>>(
      xb, cfc_t, h);
  // GEMM2: eo = h @ cproj_t^T (full K). 8*5*4 = 160 blocks.
  gemm8_kernel<1><<<NEXP * (CAP / 256) * (D / 256), 512, 0, stream>>>(
      h, cproj_t, eo);

  combine_kernel<<<T_TOK, 256, 0, stream>>>(eo, tok_slot, tok_w, out);
}

// Round 2
// 604.310 us; speedup vs baseline: 1.0517x; 1.0212x over previous
//
#include <hip/hip_runtime.h>
#include <hip/hip_bf16.h>
#include <math.h>

// Problem constants (B=4, C=1024, d=1024)
#define T_TOK 4096
#define D     1024
#define DFF   4096
#define NEXP  8
#define CAP   1280   // floor(2*1.25*4096/8)=1280, already even
#define TOPK  2

typedef __bf16 bf16x8 __attribute__((ext_vector_type(8)));
typedef float floatx4 __attribute__((ext_vector_type(4)));

__device__ __forceinline__ unsigned short f2bf(float f) {
  union { float f; unsigned u; } un; un.f = f;
  unsigned r = un.u + 0x7FFF + ((un.u >> 16) & 1);  // RNE
  return (unsigned short)(r >> 16);
}

// Branch-free erf-based exact GELU (Abramowitz-Stegun 7.1.26, |err|<=1.5e-7,
// far below bf16 quantization of h). Replaces ocml erff (~70 divergent VALU).
__device__ __forceinline__ float gelu_exact(float v) {
  float z  = v * 0.70710678118654752f;
  float az = fabsf(z);
  float t  = __builtin_amdgcn_rcpf(fmaf(0.3275911f, az, 1.0f));
  float p  = fmaf(fmaf(fmaf(fmaf(1.061405429f, t, -1.453152027f), t,
                            1.421413741f), t, -0.284496736f), t, 0.254829592f) * t;
  float ex = __expf(-z * z);
  float er = copysignf(fmaf(-p, ex, 1.0f), z);
  return 0.5f * v * (1.0f + er);
}

// ---------------------------------------------------------------------------
// Router (unchanged, verified): top-2, lowest-index tie-break, softmax.
// ---------------------------------------------------------------------------
__global__ __launch_bounds__(256) void router_kernel(
    const float* __restrict__ x, const float* __restrict__ wg,
    int* __restrict__ top_e, float* __restrict__ top_p) {
  int t = blockIdx.x * 4 + (threadIdx.x >> 6);
  int lane = threadIdx.x & 63;
  if (t >= T_TOK) return;
  const float* xr = x + (size_t)t * D;
  float acc[NEXP];
#pragma unroll
  for (int e = 0; e < NEXP; e++) acc[e] = 0.f;
  for (int dd = lane; dd < D; dd += 64) {
    float xv = xr[dd];
    const float* wr = wg + dd * NEXP;
#pragma unroll
    for (int e = 0; e < NEXP; e++) acc[e] += xv * wr[e];
  }
#pragma unroll
  for (int off = 32; off > 0; off >>= 1) {
#pragma unroll
    for (int e = 0; e < NEXP; e++) acc[e] += __shfl_xor(acc[e], off, 64);
  }
  if (lane == 0) {
    int b0 = 0; float v0 = acc[0];
    for (int e = 1; e < NEXP; e++) if (acc[e] > v0) { v0 = acc[e]; b0 = e; }
    int b1 = -1; float v1 = -INFINITY;
    for (int e = 0; e < NEXP; e++) if (e != b0 && acc[e] > v1) { v1 = acc[e]; b1 = e; }
    float e1 = expf(v1 - v0);
    float s = 1.0f + e1;
    top_e[t * 2 + 0] = b0; top_e[t * 2 + 1] = b1;
    top_p[t * 2 + 0] = 1.0f / s; top_p[t * 2 + 1] = e1 / s;
  }
}

// ---------------------------------------------------------------------------
// Rank/capacity (unchanged, verified): nanoMoE cumsum semantics via wave scans.
// ---------------------------------------------------------------------------
__global__ __launch_bounds__(1024) void rank_kernel(
    const int* __restrict__ top_e, const float* __restrict__ top_p,
    int* __restrict__ slot_token, int* __restrict__ tok_slot,
    float* __restrict__ tok_w) {
  __shared__ int wsum[16][NEXP];
  __shared__ int wscan[16][NEXP];
  int tid = threadIdx.x;
  int lane = tid & 63, w = tid >> 6;

  for (int s = tid; s < NEXP * CAP; s += 1024) slot_token[s] = -1;
  __syncthreads();  // clear visible before any assignment writes

  int base[NEXP];
#pragma unroll
  for (int e = 0; e < NEXP; e++) base[e] = 0;

  for (int k = 0; k < TOPK; k++) {
    int cnt[NEXP];
#pragma unroll
    for (int e = 0; e < NEXP; e++) cnt[e] = 0;
    int eloc[4];
#pragma unroll
    for (int i = 0; i < 4; i++) {
      int t = tid * 4 + i;
      int e = top_e[t * 2 + k];
      eloc[i] = e;
#pragma unroll
      for (int q = 0; q < NEXP; q++) cnt[q] += (q == e);
    }
    // intra-wave inclusive scan (8-wide vector), no barriers
    int inc[NEXP];
#pragma unroll
    for (int e = 0; e < NEXP; e++) inc[e] = cnt[e];
    for (int off = 1; off < 64; off <<= 1) {
#pragma unroll
      for (int e = 0; e < NEXP; e++) {
        int v = __shfl_up(inc[e], off, 64);
        if (lane >= off) inc[e] += v;
      }
    }
    if (lane == 63)
#pragma unroll
      for (int e = 0; e < NEXP; e++) wsum[w][e] = inc[e];
    __syncthreads();
    if (w == 0 && lane < 16) {
      int s[NEXP];
#pragma unroll
      for (int e = 0; e < NEXP; e++) s[e] = wsum[lane][e];
      for (int off = 1; off < 16; off <<= 1) {
#pragma unroll
        for (int e = 0; e < NEXP; e++) {
          int v = __shfl_up(s[e], off, 64);
          if (lane >= off) s[e] += v;
        }
      }
#pragma unroll
      for (int e = 0; e < NEXP; e++) wscan[lane][e] = s[e];
    }
    __syncthreads();
    int excl[NEXP];
#pragma unroll
    for (int e = 0; e < NEXP; e++)
      excl[e] = inc[e] - cnt[e] + (w ? wscan[w - 1][e] : 0) + base[e];

    int run[NEXP];
#pragma unroll
    for (int e = 0; e < NEXP; e++) run[e] = 0;
#pragma unroll
    for (int i = 0; i < 4; i++) {
      int t = tid * 4 + i;
      int e = eloc[i];
      int r = 0;
#pragma unroll
      for (int q = 0; q < NEXP; q++)
        if (q == e) { r = excl[q] + run[q]; run[q]++; }
      if (r < CAP) {
        slot_token[e * CAP + r] = t;
        tok_slot[t * 2 + k] = e * CAP + r;
      } else {
        tok_slot[t * 2 + k] = -1;
      }
      tok_w[t * 2 + k] = top_p[t * 2 + k];
    }
#pragma unroll
    for (int e = 0; e < NEXP; e++) base[e] += wscan[15][e];
    __syncthreads();  // protect wsum/wscan reuse next k
  }
}

// ---------------------------------------------------------------------------
// Gather + fp32->bf16 (unchanged, verified).
// ---------------------------------------------------------------------------
__global__ __launch_bounds__(256) void gather_cvt_kernel(
    const float* __restrict__ x, const int* __restrict__ slot_token,
    unsigned short* __restrict__ xb) {
  int slot = blockIdx.x;
  int tok = slot_token[slot];
  int i = threadIdx.x;
  float4 v = make_float4(0.f, 0.f, 0.f, 0.f);
  if (tok >= 0) v = ((const float4*)(x + (size_t)tok * D))[i];
  ushort4 o;
  o.x = f2bf(v.x); o.y = f2bf(v.y); o.z = f2bf(v.z); o.w = f2bf(v.w);
  ((ushort4*)(xb + (size_t)slot * D))[i] = o;
}

// ---------------------------------------------------------------------------
// Transpose + fp32->bf16, 64x64 tile (unchanged, verified).
// src [E][R][Cc] fp32 -> dst [E][Cc][R] bf16.
// ---------------------------------------------------------------------------
__global__ __launch_bounds__(256) void transpose_cvt_kernel(
    const float* __restrict__ src, unsigned short* __restrict__ dst,
    int R, int Cc) {
  __shared__ float tile[64][65];
  int e = blockIdx.z;
  src += (size_t)e * R * Cc;
  dst += (size_t)e * R * Cc;
  int r0 = blockIdx.y * 64, c0 = blockIdx.x * 64;
  int tr = threadIdx.x >> 4;         // 0..15
  int tc = (threadIdx.x & 15) * 4;   // 0..60
#pragma unroll
  for (int i = 0; i < 64; i += 16) {
    float4 v = *(const float4*)(src + (size_t)(r0 + tr + i) * Cc + c0 + tc);
    tile[tr + i][tc + 0] = v.x;
    tile[tr + i][tc + 1] = v.y;
    tile[tr + i][tc + 2] = v.z;
    tile[tr + i][tc + 3] = v.w;
  }
  __syncthreads();
#pragma unroll
  for (int i = 0; i < 64; i += 16) {
    int c = tr + i, r = tc;
    ushort4 o;
    o.x = f2bf(tile[r + 0][c]);
    o.y = f2bf(tile[r + 1][c]);
    o.z = f2bf(tile[r + 2][c]);
    o.w = f2bf(tile[r + 3][c]);
    *(ushort4*)(dst + (size_t)(c0 + c) * R + r0 + r) = o;
  }
}

// ---------------------------------------------------------------------------
// 256x256 8-phase bf16 MFMA GEMM, template-faithful schedule (m201 rhythm):
//   per phase: { ds_read(this phase's fragments) || stage(1 half) ->
//                sched_barrier -> s_barrier -> lgkmcnt(0) -> sched_barrier ->
//                setprio(1) 16xMFMA setprio(0) -> s_barrier }.
//   Stage cadence per K-tile: halves +6,+7,+8,+9 at phases 0..3; a single
//   counted vmcnt(4) at phase 3 (pre-barrier). At kt's phase-3 the last two
//   issued loads are halves 4kt+8,+9; vmcnt(4) therefore forces <=4kt+7
//   landed = ALL of K-tile kt+1 (halves 4kt+4..7); the phase-3 s_barrier
//   publishes them to all waves, making every pre-barrier ds_read of kt+1
//   safe, including phase 0's. Last two K-tiles use vmcnt(0) (stage() skips
//   shift the counted set).
//   Overwrite hazards: +6/+7 target the other dbuf; +8 (A kh0, current buf)
//   issues in phase-2's window, >=1 full barrier after the last kh0 A-read
//   completed (phase-1 lgkmcnt(0)); +9 (B kh0) in phase-3's window, 3 barriers
//   after the only B-kh0 reads (phase 0).
//   Bank-conflict fix (verified r1: conflicts=0): slot ^= (row>>1)&3 swizzle,
//   pre-swizzled GLOBAL source + swizzled ds_read (gload_lds dest linear).
//   MODE 0: h = gelu(xb @ cfc_t^T),   K=1024, 640 blocks (80/XCD = 1 expert).
//   MODE 1: eo = h @ cproj_t^T (fp32), K=4096, 160 blocks (20/XCD = 1 expert).
// ---------------------------------------------------------------------------
template <int MODE>
__global__ __launch_bounds__(512, 2) void gemm8_kernel(
    const unsigned short* __restrict__ A,
    const unsigned short* __restrict__ Bt,
    void* __restrict__ Cv) {
  constexpr int NN   = (MODE == 0) ? DFF : D;   // output cols
  constexpr int KK   = (MODE == 0) ? D : DFF;   // K (row stride of A and Bt)
  constexpr int NTN  = NN / 256;
  constexpr int NKT  = KK / 64;                 // K-tiles
  constexpr int STOT = NKT * 4;                 // total half-tiles
  constexpr int REG  = 256 * 32;                // shorts per (buf,khalf) region

  __shared__ unsigned short As[4 * REG];  // 64 KB
  __shared__ unsigned short Bs[4 * REG];  // 64 KB

  // XCD swizzle: nwg/8 == tiles-per-expert, so each XCD owns one expert.
  int e    = blockIdx.x & 7;
  int idx  = blockIdx.x >> 3;
  int row0 = (idx / NTN) * 256;
  int col0 = (idx % NTN) * 256;

  int tid  = threadIdx.x;
  int lane = tid & 63, wave = tid >> 6;
  int wm = wave >> 2, wn = wave & 3;      // 2 x 4 wave grid
  int fr = lane & 15, fq = lane >> 4;
  // ds_read swizzle: logical k-slot fq lives at physical slot fq^((row>>1)&3);
  // (row>>1)&3 == (fr>>1)&3 for all fragment rows (offsets are mult. of 16).
  int lanesw = (fq ^ ((fr >> 1) & 3)) * 8;  // element offset within 32-el row

  // Staging: thread t writes LDS linear slot (row=t>>2 [+128], phys=t&3);
  // source pre-swizzled so phys slot p holds logical slot p^((row>>1)&3).
  int srow  = tid >> 2;
  int lslot = (tid & 3) ^ ((srow >> 1) & 3);
  const unsigned short* asrc =
      A + (size_t)e * CAP * KK + (size_t)(row0 + srow) * KK + lslot * 8;
  const unsigned short* bsrc =
      Bt + (size_t)e * NN * KK + (size_t)(col0 + srow) * KK + lslot * 8;

  floatx4 acc[8][4];
#pragma unroll
  for (int m = 0; m < 8; m++)
#pragma unroll
    for (int n = 0; n < 4; n++) acc[m][n] = (floatx4){0.f, 0.f, 0.f, 0.f};

  // Half-tile s: kt=s>>2; s&3: 0=A kh0, 1=B kh0, 2=A kh1, 3=B kh1.
  auto stage = [&](int s) {
    if (s >= STOT) return;
    int kt = s >> 2, j = s & 3, hh = j >> 1;
    const unsigned short* src = (j & 1) ? bsrc : asrc;
    unsigned short* dst =
        ((j & 1) ? Bs : As) + ((kt & 1) * 2 + hh) * REG + tid * 8;
    size_t go = (size_t)kt * 64 + hh * 32;
    __builtin_amdgcn_global_load_lds(
        (const __attribute__((address_space(1))) unsigned int*)(src + go),
        (__attribute__((address_space(3))) unsigned int*)dst, 16, 0, 0);
    __builtin_amdgcn_global_load_lds(
        (const __attribute__((address_space(1))) unsigned int*)(src + go +
                                                               (size_t)128 * KK),
        (__attribute__((address_space(3))) unsigned int*)(dst + REG / 2), 16, 0,
        0);
  };

  // Prologue: issue halves 0..5; wait for K-tile 0 (halves 0..3) to land
  // (vmcnt(4): halves 4,5 may stay outstanding); barrier publishes.
#pragma unroll
  for (int s = 0; s < 6; s++) stage(s);
  asm volatile("s_waitcnt vmcnt(4)" ::: "memory");
  __builtin_amdgcn_s_barrier();

  bf16x8 aq[4], bq[4];

  for (int kt = 0; kt < NKT; kt++) {
    const unsigned short* a0 = As + (kt & 1) * 2 * REG;
    const unsigned short* b0 = Bs + (kt & 1) * 2 * REG;
    const unsigned short* a1 = a0 + REG;
    const unsigned short* b1 = b0 + REG;
    int abase = (wm * 128 + fr) * 32 + lanesw;
    int bbase = (wn * 64 + fr) * 32 + lanesw;

    // ---- phase 0: kh0, wave rows 0..63.
#pragma unroll
    for (int n = 0; n < 4; n++) bq[n] = *(const bf16x8*)&b0[bbase + n * 512];
#pragma unroll
    for (int m = 0; m < 4; m++) aq[m] = *(const bf16x8*)&a0[abase + m * 512];
    stage(kt * 4 + 6);
    __builtin_amdgcn_sched_barrier(0);
    __builtin_amdgcn_s_barrier();
    asm volatile("s_waitcnt lgkmcnt(0)" ::: "memory");
    __builtin_amdgcn_sched_barrier(0);
    __builtin_amdgcn_s_setprio(1);
#pragma unroll
    for (int m = 0; m < 4; m++)
#pragma unroll
      for (int n = 0; n < 4; n++)
        acc[m][n] = __builtin_amdgcn_mfma_f32_16x16x32_bf16(aq[m], bq[n],
                                                            acc[m][n], 0, 0, 0);
    __builtin_amdgcn_s_setprio(0);
    __builtin_amdgcn_s_barrier();

    // ---- phase 1: kh0, wave rows 64..127 (bq reused).
#pragma unroll
    for (int m = 0; m < 4; m++)
      aq[m] = *(const bf16x8*)&a0[abase + 2048 + m * 512];
    stage(kt * 4 + 7);
    __builtin_amdgcn_sched_barrier(0);
    __builtin_amdgcn_s_barrier();
    asm volatile("s_waitcnt lgkmcnt(0)" ::: "memory");
    __builtin_amdgcn_sched_barrier(0);
    __builtin_amdgcn_s_setprio(1);
#pragma unroll
    for (int m = 0; m < 4; m++)
#pragma unroll
      for (int n = 0; n < 4; n++)
        acc[4 + m][n] = __builtin_amdgcn_mfma_f32_16x16x32_bf16(
            aq[m], bq[n], acc[4 + m][n], 0, 0, 0);
    __builtin_amdgcn_s_setprio(0);
    __builtin_amdgcn_s_barrier();

    // ---- phase 2: kh1, wave rows 0..63.
#pragma unroll
    for (int n = 0; n < 4; n++) bq[n] = *(const bf16x8*)&b1[bbase + n * 512];
#pragma unroll
    for (int m = 0; m < 4; m++) aq[m] = *(const bf16x8*)&a1[abase + m * 512];
    stage(kt * 4 + 8);
    __builtin_amdgcn_sched_barrier(0);
    __builtin_amdgcn_s_barrier();
    asm volatile("s_waitcnt lgkmcnt(0)" ::: "memory");
    __builtin_amdgcn_sched_barrier(0);
    __builtin_amdgcn_s_setprio(1);
#pragma unroll
    for (int m = 0; m < 4; m++)
#pragma unroll
      for (int n = 0; n < 4; n++)
        acc[m][n] = __builtin_amdgcn_mfma_f32_16x16x32_bf16(aq[m], bq[n],
                                                            acc[m][n], 0, 0, 0);
    __builtin_amdgcn_s_setprio(0);
    __builtin_amdgcn_s_barrier();

    // ---- phase 3: kh1, wave rows 64..127. Counted vmcnt for next K-tile.
#pragma unroll
    for (int m = 0; m < 4; m++)
      aq[m] = *(const bf16x8*)&a1[abase + 2048 + m * 512];
    stage(kt * 4 + 9);
    if (kt >= NKT - 2)
      asm volatile("s_waitcnt vmcnt(0)" ::: "memory");
    else
      asm volatile("s_waitcnt vmcnt(4)" ::: "memory");
    __builtin_amdgcn_sched_barrier(0);
    __builtin_amdgcn_s_barrier();
    asm volatile("s_waitcnt lgkmcnt(0)" ::: "memory");
    __builtin_amdgcn_sched_barrier(0);
    __builtin_amdgcn_s_setprio(1);
#pragma unroll
    for (int m = 0; m < 4; m++)
#pragma unroll
      for (int n = 0; n < 4; n++)
        acc[4 + m][n] = __builtin_amdgcn_mfma_f32_16x16x32_bf16(
            aq[m], bq[n], acc[4 + m][n], 0, 0, 0);
    __builtin_amdgcn_s_setprio(0);
    __builtin_amdgcn_s_barrier();
  }

  // Epilogue. C/D layout: col = lane&15 (fr), row = fq*4 + reg.
  if (MODE == 0) {
    unsigned short* Ce = (unsigned short*)Cv + (size_t)e * CAP * DFF +
                         (size_t)(row0 + wm * 128 + fq * 4) * DFF + col0 +
                         wn * 64 + fr;
#pragma unroll
    for (int m = 0; m < 8; m++)
#pragma unroll
      for (int r = 0; r < 4; r++) {
        size_t ro = (size_t)(m * 16 + r) * DFF;
#pragma unroll
        for (int n = 0; n < 4; n++)
          Ce[ro + n * 16] = f2bf(gelu_exact(acc[m][n][r]));
      }
  } else {
    float* Ce = (float*)Cv + (size_t)e * CAP * D +
                (size_t)(row0 + wm * 128 + fq * 4) * D + col0 + wn * 64 + fr;
#pragma unroll
    for (int m = 0; m < 8; m++)
#pragma unroll
      for (int r = 0; r < 4; r++) {
        size_t ro = (size_t)(m * 16 + r) * D;
#pragma unroll
        for (int n = 0; n < 4; n++) Ce[ro + n * 16] = acc[m][n][r];
      }
  }
}

// ---------------------------------------------------------------------------
// Combine: out[t,:] = sum_k kept(w_k * eo[slot_k,:]). Single eo (no split-K).
// ---------------------------------------------------------------------------
__global__ __launch_bounds__(256) void combine_kernel(
    const float* __restrict__ eo, const int* __restrict__ tok_slot,
    const float* __restrict__ tok_w, float* __restrict__ out) {
  int t = blockIdx.x;
  int i = threadIdx.x;
  float4 acc = make_float4(0.f, 0.f, 0.f, 0.f);
#pragma unroll
  for (int k = 0; k < TOPK; k++) {
    int s = tok_slot[t * 2 + k];
    if (s >= 0) {
      float w = tok_w[t * 2 + k];
      float4 v = ((const float4*)(eo + (size_t)s * D))[i];
      acc.x += w * v.x;
      acc.y += w * v.y;
      acc.z += w * v.z;
      acc.w += w * v.w;
    }
  }
  ((float4*)(out + (size_t)t * D))[i] = acc;
}

// ---------------------------------------------------------------------------
extern "C" void kernel_launch(void* const* d_in, const int* in_sizes, int n_in,
                              void* d_out, int out_size, void* d_ws, size_t ws_size,
                              hipStream_t stream) {
  const float* x     = (const float*)d_in[0];  // [4,1024,1024]
  const float* wg    = (const float*)d_in[1];  // [1024,8]
  const float* cfc   = (const float*)d_in[2];  // [8,1024,4096]
  const float* cproj = (const float*)d_in[3];  // [8,4096,1024]
  float* out = (float*)d_out;

  char* ws = (char*)d_ws;
  size_t off = 0;
  auto alloc = [&](size_t bytes) -> void* {
    void* p = ws + off;
    off += (bytes + 255) & ~(size_t)255;
    return p;
  };
  int*   top_e      = (int*)  alloc((size_t)T_TOK * 2 * 4);
  float* top_p      = (float*)alloc((size_t)T_TOK * 2 * 4);
  int*   slot_token = (int*)  alloc((size_t)NEXP * CAP * 4);
  int*   tok_slot   = (int*)  alloc((size_t)T_TOK * 2 * 4);
  float* tok_w      = (float*)alloc((size_t)T_TOK * 2 * 4);
  unsigned short* xb      = (unsigned short*)alloc((size_t)NEXP * CAP * D * 2);   // 20 MB
  unsigned short* cfc_t   = (unsigned short*)alloc((size_t)NEXP * D * DFF * 2);   // 67 MB [e][DFF][D]
  unsigned short* cproj_t = (unsigned short*)alloc((size_t)NEXP * DFF * D * 2);   // 67 MB [e][D][DFF]
  unsigned short* h       = (unsigned short*)alloc((size_t)NEXP * CAP * DFF * 2); // 84 MB
  // eo [NEXP][CAP][D] fp32 = 42 MB, aliases dead xb/cfc_t region (87.9 MB):
  // GEMM2 reads only h + cproj_t; combine reads eo.
  float* eo = (float*)xb;

  // Weight convert+transpose (independent of routing).
  transpose_cvt_kernel<<<dim3(DFF / 64, D / 64, NEXP), 256, 0, stream>>>(
      cfc, cfc_t, D, DFF);
  transpose_cvt_kernel<<<dim3(D / 64, DFF / 64, NEXP), 256, 0, stream>>>(
      cproj, cproj_t, DFF, D);

  router_kernel<<<T_TOK / 4, 256, 0, stream>>>(x, wg, top_e, top_p);
  rank_kernel<<<1, 1024, 0, stream>>>(top_e, top_p, slot_token, tok_slot, tok_w);
  gather_cvt_kernel<<<NEXP * CAP, 256, 0, stream>>>(x, slot_token, xb);

  // GEMM1: h = gelu(xb @ cfc_t^T). 8*5*16 = 640 blocks.
  gemm8_kernel<0><<<NEXP * (CAP / 256) * (DFF / 256), 512, 0, stream>>>(
      xb, cfc_t, h);
  // GEMM2: eo = h @ cproj_t^T (full K). 8*5*4 = 160 blocks.
  gemm8_kernel<1><<<NEXP * (CAP / 256) * (D / 256), 512, 0, stream>>>(
      h, cproj_t, eo);

  combine_kernel<<<T_TOK, 256, 0, stream>>>(eo, tok_slot, tok_w, out);
}